// Round 3
// baseline (3550.661 us; speedup 1.0000x reference)
//
#include <hip/hip_runtime.h>
#include <cmath>

// TimeLSTMCell B=64, S=512, E=256, H=512.
// Round 7 (from round-6 @2008us): critical-path surgery.
//  * x-GEMM (8 of 24 k-steps) moved OFF the recurrent critical path: computed
//    during the flag-propagation window of the previous step, seeds the gate
//    accumulator. x frags loaded direct from global (L1/L2-hot, fp32) and
//    packed with v_cvt_pk_bf16_f32 (1 instr / 2 elems). x_sb staging deleted.
//  * Per-thread producer-specific poll: each staging thread depends on exactly
//    one producer WG (sc32>>1); it polls THAT flag then loads its slice.
//    Fast producers' data streams in while stragglers finish (load RT overlaps
//    the convoy). Own-WG slices skip the poll. Removes the t<16 poll phase
//    and one barrier.
//  * d-reduce + cs1v phase folded into the finale (each thread sums its own
//    4 Dred partials) -> one fewer barrier + LDS round trip.
//  * LDS bank-conflict floor: h_sb/c_sb pitch exactly 1024 B with 16-B-granule
//    XOR swizzle (p = g ^ (row&7)) applied at stage-write and frag-read;
//    act[] swizzled ((jj+m)&31). Stage writes are two lane-contiguous b128s.
//  * decay table (16x512 f32, 32 KB LDS) precomputed once -> ts load + logf
//    off the per-step path.
// Barriers/step: 3 (was 4 + poll). Sync mechanics otherwise identical to
// round 6 (relaxed AGENT-scope atomics, double-buffered bf16 mirrors, padded
// flags, monotonic step tags).
//
// MFMA 16x16x32 bf16 layouts (m89/m91/m120 verified):
//   A: m=lane&15, k=(lane>>4)*8+j   B: n=lane&15, k=(lane>>4)*8+j
//   D: n=lane&15, m=(lane>>4)*4+reg

typedef short bf16x8 __attribute__((ext_vector_type(8)));
typedef float f32x4  __attribute__((ext_vector_type(4)));

#define Bdim 64
#define Sdim 512
#define Edim 256
#define Hdim 512
#define NWG  64
#define NT   512
#define FSTR 16

// ws layout (bytes), identical to round 6. Total ~3.95 MB.
#define WS_FLAGS 0
#define WS_HMIR0 16384
#define WS_HMIR1 (WS_HMIR0 + 65536)
#define WS_CMIR0 (WS_HMIR1 + 65536)
#define WS_CMIR1 (WS_CMIR0 + 65536)
#define WS_WFRAG (WS_CMIR1 + 65536)       // 16cg*8wv*24k*64lane*8 bf16 = 3 MB
#define WS_DFRAG (WS_WFRAG + 3145728)     // 16cg*8wv*4k*64lane*8 bf16 = 512 KB

__device__ __forceinline__ unsigned ld_dev_u32(const unsigned* p) {
    return __hip_atomic_load(p, __ATOMIC_RELAXED, __HIP_MEMORY_SCOPE_AGENT);
}
__device__ __forceinline__ void st_dev_u32(unsigned* p, unsigned v) {
    __hip_atomic_store(p, v, __ATOMIC_RELAXED, __HIP_MEMORY_SCOPE_AGENT);
}
__device__ __forceinline__ unsigned long long ld_dev_u64(const unsigned long long* p) {
    return __hip_atomic_load(p, __ATOMIC_RELAXED, __HIP_MEMORY_SCOPE_AGENT);
}
__device__ __forceinline__ unsigned short f2bf(float f) {
    union { float f; unsigned u; } v; v.f = f;
    return (unsigned short)((v.u + 0x7FFFu + ((v.u >> 16) & 1u)) >> 16);  // RNE
}
__device__ __forceinline__ unsigned pack2(float lo, float hi) {
    return (unsigned)f2bf(lo) | ((unsigned)f2bf(hi) << 16);
}
__device__ __forceinline__ float fast_tanh(float x) {
    const float ax = __builtin_fabsf(x);
    const float e  = __expf(-2.0f * ax);
    const float t  = (1.0f - e) / (1.0f + e);
    return __builtin_copysignf(t, x);
}
__device__ __forceinline__ float fast_sigmoid(float x) {
    return 1.0f / (1.0f + __expf(-x));
}

// ---------------- pre-pass: pack weights, zero mirrors/flags ----------------
__global__ __launch_bounds__(256) void tlstm_prep(
    const float* __restrict__ Wall, const float* __restrict__ Uall,
    const float* __restrict__ Wd, unsigned char* __restrict__ ws)
{
    const int w = blockIdx.x, t = threadIdx.x;
    unsigned short* Wfrag = (unsigned short*)(ws + WS_WFRAG);
    unsigned short* Dfrag = (unsigned short*)(ws + WS_DFRAG);
    const int l = t & 63, ks = t >> 6, nn = l & 15, q = l >> 4;

    if (w < 128) {                       // gate fragments: WG = (cg, wv)
        const int cg = w >> 3, wv = w & 7;
        const int G = wv * 16 + nn, g = G >> 5, jj = G & 31;
        const int row = g * Hdim + cg * 32 + jj;
        for (int i = 0; i < 6; ++i) {
            const int kp = ks * 6 + i;   // 0..23
            const float* src = (kp < 16)
                ? Wall + (size_t)row * Hdim + kp * 32 + q * 8
                : Uall + (size_t)row * Edim + (kp - 16) * 32 + q * 8;
            unsigned* dst = (unsigned*)(Wfrag
                + (((size_t)(cg * 8 + wv) * 24 + kp) * 64 + l) * 8);
            #pragma unroll
            for (int p = 0; p < 4; ++p) dst[p] = pack2(src[2*p], src[2*p+1]);
        }
    } else if (w < 192) {                // d fragments: 64 WGs, 8 frags each
        const int u = w - 128, cg = u >> 2, q4 = u & 3;
        for (int half = 0; half < 2; ++half) {
            const int wv = q4 * 2 + half;        // 0..7
            const int i  = ks;                   // 0..3
            const int dt = wv >> 2, kd = (wv & 3) * 4 + i;
            const int row = cg * 32 + dt * 16 + nn;     // Wd output col
            const float* src = Wd + (size_t)row * Hdim + kd * 32 + q * 8;
            unsigned* dst = (unsigned*)(Dfrag
                + (((size_t)(cg * 8 + wv) * 4 + i) * 64 + l) * 8);
            #pragma unroll
            for (int p = 0; p < 4; ++p) dst[p] = pack2(src[2*p], src[2*p+1]);
        }
    } else {                             // zero flags + all 4 mirrors (278528 B)
        const int idx = (w - 192) * 256 + t;          // 0..16383
        uint4* z = (uint4*)ws;
        for (int i = idx; i < 17408; i += 16384) z[i] = make_uint4(0, 0, 0, 0);
        // mirror parity-0 zeros ARE the valid step-0 state (h=c=0).
    }
}

// ------------------------------- main kernel --------------------------------
__global__ __launch_bounds__(NT, 2) void tlstm_mfma(
    const float* __restrict__ x,       // [B,S,E] fp32
    const float* __restrict__ ts,      // [B,S]
    const float* __restrict__ Wall_b,  // [4H]
    const float* __restrict__ Uall_b,  // [4H]
    const float* __restrict__ Wd_b,    // [H]
    float* __restrict__ out,           // [B,S,H] | h_f | c_f (write-only)
    unsigned char* __restrict__ ws)
{
    // h/c tiles: 16 rows x 512 bf16, pitch exactly 1024 B, granule-swizzled.
    __shared__ __align__(16) unsigned short h_sb[16 * 512];
    __shared__ __align__(16) unsigned short c_sb[16 * 512];
    __shared__ float Dred[2][4][256];
    __shared__ float act[4 * 512];              // [gate][m*32 + ((jj+m)&31)]
    __shared__ float dectab[16 * 512];          // [batch][s]

    int* flags = (int*)(ws + WS_FLAGS);
    const unsigned short* Wfrag = (const unsigned short*)(ws + WS_WFRAG);
    const unsigned short* Dfrag = (const unsigned short*)(ws + WS_DFRAG);

    const int t    = threadIdx.x;
    const int bg   = blockIdx.x >> 4, cg = blockIdx.x & 15;
    const int b0   = bg * 16, j0 = cg * 32;
    const int w    = t >> 6, lane = t & 63, q = lane >> 4, nn = lane & 15;

    // gate-col identity of this lane (wave w owns gate-col tile w: 16 cols)
    const int G = w * 16 + nn, g = G >> 5, jj = G & 31;
    const float bias_g = Wall_b[g * Hdim + j0 + jj] + Uall_b[g * Hdim + j0 + jj];
    // finale identity: unit t -> (batch fm, col fj)
    const int fm = t >> 5, fj = t & 31;
    const int fdt = fj >> 4, fn = fj & 15;
    const float bias_d = Wd_b[j0 + fj];

    // ---- weights -> registers/AGPRs, once (L2-hot loads) ----
    bf16x8 bw[24];
    #pragma unroll
    for (int i = 0; i < 24; ++i)
        bw[i] = *(const bf16x8*)(Wfrag
            + (((size_t)(cg * 8 + w) * 24 + i) * 64 + lane) * 8);
    bf16x8 bd[4];
    #pragma unroll
    for (int i = 0; i < 4; ++i)
        bd[i] = *(const bf16x8*)(Dfrag
            + (((size_t)(cg * 8 + w) * 4 + i) * 64 + lane) * 8);

    // staging identity: row srow, 16-col chunk sc32; producer WG = sc32>>1
    const int srow = t >> 5, sc32 = t & 31;
    const int prod = sc32 >> 1;
    const bool own = (prod == cg);

    // ---- decay table: off the per-step path ----
    for (int i = t; i < 16 * Sdim; i += NT)
        dectab[i] = 1.0f / __logf(2.7182818284590452f
                                  + ts[(size_t)(b0 + (i >> 9)) * Sdim + (i & 511)]);

    // x contribution for step sx (8 MFMA k-steps), direct-from-global fp32
    auto xmfma = [&](int sx) -> f32x4 {
        f32x4 a = {0.f, 0.f, 0.f, 0.f};
        const float* xb = x + ((size_t)(b0 + nn) * Sdim + sx) * Edim + q * 8;
        #pragma unroll
        for (int kk = 0; kk < 8; ++kk) {
            float4 v0 = *(const float4*)(xb + kk * 32);
            float4 v1 = *(const float4*)(xb + kk * 32 + 4);
            union { unsigned u[4]; bf16x8 v; } cv;
            asm("v_cvt_pk_bf16_f32 %0, %1, %2" : "=v"(cv.u[0]) : "v"(v0.x), "v"(v0.y));
            asm("v_cvt_pk_bf16_f32 %0, %1, %2" : "=v"(cv.u[1]) : "v"(v0.z), "v"(v0.w));
            asm("v_cvt_pk_bf16_f32 %0, %1, %2" : "=v"(cv.u[2]) : "v"(v1.x), "v"(v1.y));
            asm("v_cvt_pk_bf16_f32 %0, %1, %2" : "=v"(cv.u[3]) : "v"(v1.z), "v"(v1.w));
            a = __builtin_amdgcn_mfma_f32_16x16x32_bf16(cv.v, bw[16 + kk], a, 0, 0, 0);
        }
        return a;
    };

    // stage h,c for step si: per-thread poll of OWN producer, then load slice
    auto stage_hc = [&](int si) {
        if (!own) {
            const unsigned* fp = (const unsigned*)(flags + (bg * 16 + prod) * FSTR);
            while ((int)ld_dev_u32(fp) < si) __builtin_amdgcn_s_sleep(1);
        }
        const unsigned long long* hsrc =
            (const unsigned long long*)(ws + WS_HMIR0 + (si & 1) * 65536);
        const unsigned long long* csrc =
            (const unsigned long long*)(ws + WS_CMIR0 + (si & 1) * 65536);
        const size_t goff = (size_t)(b0 + srow) * 128 + sc32 * 4;   // u64 index
        unsigned long long hv[4], cv[4];
        #pragma unroll
        for (int i = 0; i < 4; ++i) hv[i] = ld_dev_u64(hsrc + goff + i);
        #pragma unroll
        for (int i = 0; i < 4; ++i) cv[i] = ld_dev_u64(csrc + goff + i);
        // granule-swizzled LDS writes, two lane-contiguous b128s per array
        const int p0 = (2 * sc32) ^ (srow & 7), p1 = (2 * sc32 + 1) ^ (srow & 7);
        unsigned* hl = (unsigned*)h_sb + srow * 256;
        unsigned* cl = (unsigned*)c_sb + srow * 256;
        *(uint4*)(hl + p0 * 4) = make_uint4((unsigned)hv[0], (unsigned)(hv[0] >> 32),
                                            (unsigned)hv[1], (unsigned)(hv[1] >> 32));
        *(uint4*)(hl + p1 * 4) = make_uint4((unsigned)hv[2], (unsigned)(hv[2] >> 32),
                                            (unsigned)hv[3], (unsigned)(hv[3] >> 32));
        *(uint4*)(cl + p0 * 4) = make_uint4((unsigned)cv[0], (unsigned)(cv[0] >> 32),
                                            (unsigned)cv[1], (unsigned)(cv[1] >> 32));
        *(uint4*)(cl + p1 * 4) = make_uint4((unsigned)cv[2], (unsigned)(cv[2] >> 32),
                                            (unsigned)cv[3], (unsigned)(cv[3] >> 32));
    };

    float c_reg = 0.0f;                        // fp32 c carry for own unit
    f32x4 accx = xmfma(0);
    stage_hc(0);                               // flags are 0 -> no wait
    __syncthreads();

    for (int s = 0;; ++s) {
        // ---- critical-path MFMA: 16 h-steps (2 chains) + 4 d-steps ----
        f32x4 acc0 = {0.f, 0.f, 0.f, 0.f}, acc1 = {0.f, 0.f, 0.f, 0.f};
        f32x4 accd = {0.f, 0.f, 0.f, 0.f};
        #pragma unroll
        for (int i = 0; i < 8; ++i) {
            bf16x8 av = *(const bf16x8*)(h_sb + nn * 512
                + (((i * 4 + q) ^ (nn & 7)) * 8));
            acc0 = __builtin_amdgcn_mfma_f32_16x16x32_bf16(av, bw[i], acc0, 0, 0, 0);
        }
        #pragma unroll
        for (int i = 8; i < 16; ++i) {
            bf16x8 av = *(const bf16x8*)(h_sb + nn * 512
                + (((i * 4 + q) ^ (nn & 7)) * 8));
            acc1 = __builtin_amdgcn_mfma_f32_16x16x32_bf16(av, bw[i], acc1, 0, 0, 0);
        }
        #pragma unroll
        for (int i = 0; i < 4; ++i) {
            const int kd = (w & 3) * 4 + i;
            bf16x8 av = *(const bf16x8*)(c_sb + nn * 512
                + (((kd * 4 + q) ^ (nn & 7)) * 8));
            accd = __builtin_amdgcn_mfma_f32_16x16x32_bf16(av, bd[i], accd, 0, 0, 0);
        }

        // ---- gate activations in-register, spill act + Dred (swizzled) ----
        const int dt = w >> 2;
        #pragma unroll
        for (int r = 0; r < 4; ++r) {
            const int m = q * 4 + r;
            const float sv = acc0[r] + acc1[r] + accx[r] + bias_g;
            act[g * 512 + m * 32 + ((jj + m) & 31)] =
                (g == 3) ? fast_tanh(sv) : fast_sigmoid(sv);
            Dred[dt][w & 3][m * 16 + ((nn + m) & 15)] = accd[r];
        }
        __syncthreads();                                   // A

        // ---- finale: all 512 threads, one (batch,col) unit; d-reduce folded
        {
            const int sl = fm * 16 + ((fn + fm) & 15);
            const float dsum = Dred[fdt][0][sl] + Dred[fdt][1][sl]
                             + Dred[fdt][2][sl] + Dred[fdt][3][sl];
            const float cs1  = fast_tanh(dsum + bias_d);
            const float dec  = dectab[fm * 512 + s];
            const float cadj = (c_reg - cs1) + cs1 * dec;
            const int   ai   = fm * 32 + ((fj + fm) & 31);
            const float f  = act[ai];
            const float ii = act[512 + ai];
            const float oo = act[1024 + ai];
            const float gg = act[1536 + ai];
            const float cn = f * cadj + ii * gg;
            const float hn = oo * fast_tanh(cn);
            c_reg = cn;
            const float hn1 = __shfl_down(hn, 1);
            const float cn1 = __shfl_down(cn, 1);
            if (s < Sdim - 1) {
                if ((t & 1) == 0) {        // mirror stores FIRST (critical path)
                    unsigned* hmw = (unsigned*)(ws + WS_HMIR0 + ((s + 1) & 1) * 65536);
                    unsigned* cmw = (unsigned*)(ws + WS_CMIR0 + ((s + 1) & 1) * 65536);
                    const int didx = ((b0 + fm) * Hdim + j0 + fj) >> 1;
                    st_dev_u32(hmw + didx, pack2(hn, hn1));
                    st_dev_u32(cmw + didx, pack2(cn, cn1));
                }
            } else {
                float* hf = out + (size_t)Bdim * Sdim * Hdim;
                float* cf = hf + (size_t)Bdim * Hdim;
                hf[(b0 + fm) * Hdim + j0 + fj] = hn;
                cf[(b0 + fm) * Hdim + j0 + fj] = cn;
            }
            out[((size_t)(b0 + fm) * Sdim + s) * Hdim + j0 + fj] = hn;
        }

        if (s == Sdim - 1) break;

        asm volatile("s_waitcnt vmcnt(0)" ::: "memory");   // mirror stores at LIC
        __syncthreads();                                   // B
        if (t == 0)
            st_dev_u32((unsigned*)(flags + blockIdx.x * FSTR), (unsigned)(s + 1));

        // off-critical-path work while the flag propagates:
        accx = xmfma(s + 1);       // x contribution for next step
        stage_hc(s + 1);           // per-producer poll + slice load
        __syncthreads();                                   // D
    }
}

extern "C" void kernel_launch(void* const* d_in, const int* in_sizes, int n_in,
                              void* d_out, int out_size, void* d_ws, size_t ws_size,
                              hipStream_t stream) {
    const float* x      = (const float*)d_in[0];
    const float* ts     = (const float*)d_in[1];
    const float* Wall   = (const float*)d_in[2];
    const float* Wall_b = (const float*)d_in[3];
    const float* Uall   = (const float*)d_in[4];
    const float* Uall_b = (const float*)d_in[5];
    const float* Wd     = (const float*)d_in[6];
    const float* Wd_b   = (const float*)d_in[7];

    tlstm_prep<<<256, 256, 0, stream>>>(Wall, Uall, Wd, (unsigned char*)d_ws);
    tlstm_mfma<<<NWG, NT, 0, stream>>>(x, ts, Wall_b, Uall_b, Wd_b,
                                       (float*)d_out, (unsigned char*)d_ws);
}